// Round 1
// baseline (1184.959 us; speedup 1.0000x reference)
//
#include <hip/hip_runtime.h>

#define N_NODES 10000
#define D 128
#define N_EDGES 640000

// One edge per 32-thread group; each thread moves a float4 (4 feats) and
// issues 4 atomicAdds into the destination row.
__global__ __launch_bounds__(256) void gcn_scatter_kernel(
    const float* __restrict__ x,
    const int* __restrict__ src,
    const int* __restrict__ dst,
    float* __restrict__ h) {
  int gid = blockIdx.x * blockDim.x + threadIdx.x;
  int edge = gid >> 5;          // 32 threads per edge
  int f4   = gid & 31;          // float4 index within the 128-float row
  if (edge >= N_EDGES) return;
  int s = src[edge];
  int d = dst[edge];
  const float4 v = ((const float4*)(x + (size_t)s * D))[f4];
  float* hp = h + (size_t)d * D + (size_t)f4 * 4;
  atomicAdd(hp + 0, v.x);
  atomicAdd(hp + 1, v.y);
  atomicAdd(hp + 2, v.z);
  atomicAdd(hp + 3, v.w);
}

// out = relu(h @ W + b). W staged in LDS (64 KB). 16 rows per block,
// 256 threads: col = tid&127, two row-slots interleaved.
__global__ __launch_bounds__(256) void gcn_gemm_kernel(
    const float* __restrict__ h,
    const float* __restrict__ W,
    const float* __restrict__ b,
    float* __restrict__ out) {
  __shared__ float Wl[D * D];   // 64 KB
  for (int i = threadIdx.x; i < D * D; i += 256) Wl[i] = W[i];
  __syncthreads();

  const int col  = threadIdx.x & (D - 1);
  const int rsub = threadIdx.x >> 7;   // 0 or 1
  const int row0 = blockIdx.x * 16;
  const float bias = b[col];

  for (int r = rsub; r < 16; r += 2) {
    const int row = row0 + r;
    if (row >= N_NODES) continue;
    const float* hr = h + (size_t)row * D;
    float acc = bias;
#pragma unroll 8
    for (int k = 0; k < D; ++k) {
      acc = fmaf(hr[k], Wl[k * D + col], acc);
    }
    out[(size_t)row * D + col] = fmaxf(acc, 0.0f);
  }
}

extern "C" void kernel_launch(void* const* d_in, const int* in_sizes, int n_in,
                              void* d_out, int out_size, void* d_ws, size_t ws_size,
                              hipStream_t stream) {
  const float* x   = (const float*)d_in[0];
  const int*   src = (const int*)d_in[1];
  const int*   dst = (const int*)d_in[2];
  const float* W   = (const float*)d_in[3];
  const float* b   = (const float*)d_in[4];
  float* out = (float*)d_out;
  float* h   = (float*)d_ws;   // N_NODES * D floats = 5.12 MB

  hipMemsetAsync(h, 0, (size_t)N_NODES * D * sizeof(float), stream);

  // 640000 edges * 32 threads / 256 = 80000 blocks
  const int scatter_blocks = (N_EDGES * 32) / 256;
  gcn_scatter_kernel<<<scatter_blocks, 256, 0, stream>>>(x, src, dst, h);

  const int gemm_blocks = (N_NODES + 15) / 16;   // 625
  gcn_gemm_kernel<<<gemm_blocks, 256, 0, stream>>>(h, W, b, out);
}

// Round 2
// 252.561 us; speedup vs baseline: 4.6918x; 4.6918x over previous
//
#include <hip/hip_runtime.h>

#define N_NODES 10000
#define D 128
#define N_EDGES 640000
#define SCAN_THREADS 1024
#define SCAN_CHUNK 10   // 1024*10 = 10240 >= 10000

// ---- Pass 1: histogram of dst -> counts ----
__global__ __launch_bounds__(256) void gcn_hist_kernel(
    const int* __restrict__ dst, int* __restrict__ counts) {
  int e = blockIdx.x * blockDim.x + threadIdx.x;
  if (e < N_EDGES) atomicAdd(&counts[dst[e]], 1);
}

// ---- Pass 2: single-block exclusive scan of counts -> off, cursor ----
__global__ __launch_bounds__(SCAN_THREADS) void gcn_scan_kernel(
    int* __restrict__ counts,   // in: counts, out: exclusive offsets (off)
    int* __restrict__ cursor) { // out: copy of offsets (running cursors)
  __shared__ int part[SCAN_THREADS];
  const int t = threadIdx.x;
  int local[SCAN_CHUNK];
  int sum = 0;
  const int base = t * SCAN_CHUNK;
#pragma unroll
  for (int j = 0; j < SCAN_CHUNK; ++j) {
    int idx = base + j;
    int c = (idx < N_NODES) ? counts[idx] : 0;
    local[j] = c;
    sum += c;
  }
  part[t] = sum;
  __syncthreads();
  // Hillis-Steele inclusive scan over 1024 partials
  for (int ofs = 1; ofs < SCAN_THREADS; ofs <<= 1) {
    int v = (t >= ofs) ? part[t - ofs] : 0;
    __syncthreads();
    part[t] += v;
    __syncthreads();
  }
  int run = part[t] - sum;  // exclusive base for this chunk
#pragma unroll
  for (int j = 0; j < SCAN_CHUNK; ++j) {
    int idx = base + j;
    if (idx < N_NODES) {
      counts[idx] = run;
      cursor[idx] = run;
      run += local[j];
    }
  }
  if (t == SCAN_THREADS - 1) counts[N_NODES] = part[SCAN_THREADS - 1];
}

// ---- Pass 3: scatter src ids into dst-sorted order ----
__global__ __launch_bounds__(256) void gcn_fill_kernel(
    const int* __restrict__ src, const int* __restrict__ dst,
    int* __restrict__ cursor, int* __restrict__ srcs_sorted) {
  int e = blockIdx.x * blockDim.x + threadIdx.x;
  if (e < N_EDGES) {
    int slot = atomicAdd(&cursor[dst[e]], 1);
    srcs_sorted[slot] = src[e];
  }
}

// ---- Pass 4: per-node gather-sum, no atomics ----
// 256 threads = 2 nodes/block, 128 threads (one per feature) per node.
__global__ __launch_bounds__(256) void gcn_gather_kernel(
    const float* __restrict__ x, const int* __restrict__ off,
    const int* __restrict__ srcs_sorted, float* __restrict__ h) {
  const int node = blockIdx.x * 2 + (threadIdx.x >> 7);
  const int col  = threadIdx.x & (D - 1);
  if (node >= N_NODES) return;
  const int i0 = off[node];
  const int i1 = off[node + 1];
  float a0 = 0.f, a1 = 0.f, a2 = 0.f, a3 = 0.f;
  int i = i0;
  for (; i + 4 <= i1; i += 4) {
    int s0 = srcs_sorted[i + 0];
    int s1 = srcs_sorted[i + 1];
    int s2 = srcs_sorted[i + 2];
    int s3 = srcs_sorted[i + 3];
    a0 += x[(size_t)s0 * D + col];
    a1 += x[(size_t)s1 * D + col];
    a2 += x[(size_t)s2 * D + col];
    a3 += x[(size_t)s3 * D + col];
  }
  for (; i < i1; ++i) a0 += x[(size_t)srcs_sorted[i] * D + col];
  h[(size_t)node * D + col] = (a0 + a1) + (a2 + a3);
}

// ---- Pass 5: out = relu(h @ W + b), W staged in LDS ----
__global__ __launch_bounds__(256) void gcn_gemm_kernel(
    const float* __restrict__ h, const float* __restrict__ W,
    const float* __restrict__ b, float* __restrict__ out) {
  __shared__ float Wl[D * D];   // 64 KB
  for (int i = threadIdx.x; i < D * D; i += 256) Wl[i] = W[i];
  __syncthreads();

  const int col  = threadIdx.x & (D - 1);
  const int rsub = threadIdx.x >> 7;
  const int row0 = blockIdx.x * 16;
  const float bias = b[col];

  for (int r = rsub; r < 16; r += 2) {
    const int row = row0 + r;
    if (row >= N_NODES) continue;
    const float* hr = h + (size_t)row * D;
    float acc = bias;
#pragma unroll 8
    for (int k = 0; k < D; ++k) {
      acc = fmaf(hr[k], Wl[k * D + col], acc);
    }
    out[(size_t)row * D + col] = fmaxf(acc, 0.0f);
  }
}

extern "C" void kernel_launch(void* const* d_in, const int* in_sizes, int n_in,
                              void* d_out, int out_size, void* d_ws, size_t ws_size,
                              hipStream_t stream) {
  const float* x   = (const float*)d_in[0];
  const int*   src = (const int*)d_in[1];
  const int*   dst = (const int*)d_in[2];
  const float* W   = (const float*)d_in[3];
  const float* b   = (const float*)d_in[4];
  float* out = (float*)d_out;

  // Workspace layout
  float* h      = (float*)d_ws;                       // 1,280,000 floats
  int*   off    = (int*)(h + (size_t)N_NODES * D);    // 10001 ints (counts -> offsets)
  int*   cursor = off + 10016;                        // 10000 ints
  int*   srcs   = cursor + 10016;                     // 640,000 ints

  hipMemsetAsync(h, 0, (size_t)N_NODES * D * sizeof(float), stream);
  hipMemsetAsync(off, 0, 10016 * sizeof(int), stream);

  const int eblocks = (N_EDGES + 255) / 256;  // 2500
  gcn_hist_kernel<<<eblocks, 256, 0, stream>>>(dst, off);
  gcn_scan_kernel<<<1, SCAN_THREADS, 0, stream>>>(off, cursor);
  gcn_fill_kernel<<<eblocks, 256, 0, stream>>>(src, dst, cursor, srcs);
  gcn_gather_kernel<<<(N_NODES + 1) / 2, 256, 0, stream>>>(x, off, srcs, h);
  gcn_gemm_kernel<<<(N_NODES + 15) / 16, 256, 0, stream>>>(h, W, b, out);
}

// Round 3
// 193.406 us; speedup vs baseline: 6.1268x; 1.3059x over previous
//
#include <hip/hip_runtime.h>

#define N_NODES 10000
#define D 128
#define N_EDGES 640000
#define SCAN_THREADS 1024
#define SCAN_CHUNK 10   // 1024*10 = 10240 >= 10000

// ---- Pass 1: histogram of dst -> counts ----
__global__ __launch_bounds__(256) void gcn_hist_kernel(
    const int* __restrict__ dst, int* __restrict__ counts) {
  int e = blockIdx.x * blockDim.x + threadIdx.x;
  if (e < N_EDGES) atomicAdd(&counts[dst[e]], 1);
}

// ---- Pass 2: single-block exclusive scan of counts -> off, cursor ----
__global__ __launch_bounds__(SCAN_THREADS) void gcn_scan_kernel(
    int* __restrict__ counts,   // in: counts, out: exclusive offsets (off)
    int* __restrict__ cursor) { // out: copy of offsets (running cursors)
  __shared__ int part[SCAN_THREADS];
  const int t = threadIdx.x;
  int local[SCAN_CHUNK];
  int sum = 0;
  const int base = t * SCAN_CHUNK;
#pragma unroll
  for (int j = 0; j < SCAN_CHUNK; ++j) {
    int idx = base + j;
    int c = (idx < N_NODES) ? counts[idx] : 0;
    local[j] = c;
    sum += c;
  }
  part[t] = sum;
  __syncthreads();
  for (int ofs = 1; ofs < SCAN_THREADS; ofs <<= 1) {
    int v = (t >= ofs) ? part[t - ofs] : 0;
    __syncthreads();
    part[t] += v;
    __syncthreads();
  }
  int run = part[t] - sum;  // exclusive base for this chunk
#pragma unroll
  for (int j = 0; j < SCAN_CHUNK; ++j) {
    int idx = base + j;
    if (idx < N_NODES) {
      counts[idx] = run;
      cursor[idx] = run;
      run += local[j];
    }
  }
  if (t == SCAN_THREADS - 1) counts[N_NODES] = part[SCAN_THREADS - 1];
}

// ---- Pass 3: scatter src ids into dst-sorted order ----
__global__ __launch_bounds__(256) void gcn_fill_kernel(
    const int* __restrict__ src, const int* __restrict__ dst,
    int* __restrict__ cursor, int* __restrict__ srcs_sorted) {
  int e = blockIdx.x * blockDim.x + threadIdx.x;
  if (e < N_EDGES) {
    int slot = atomicAdd(&cursor[dst[e]], 1);
    srcs_sorted[slot] = src[e];
  }
}

// ---- Pass 4: per-node gather-sum, no atomics ----
// 32 threads per node (one float4 per thread), 8 nodes per 256-block.
__global__ __launch_bounds__(256) void gcn_gather_kernel(
    const float* __restrict__ x, const int* __restrict__ off,
    const int* __restrict__ srcs_sorted, float* __restrict__ h) {
  const int node = blockIdx.x * 8 + (threadIdx.x >> 5);
  const int f   = (threadIdx.x & 31) * 4;
  if (node >= N_NODES) return;
  const int i0 = off[node];
  const int i1 = off[node + 1];
  float4 a0 = {0.f, 0.f, 0.f, 0.f}, a1 = a0, a2 = a0, a3 = a0;
  int i = i0;
  for (; i + 4 <= i1; i += 4) {
    int s0 = srcs_sorted[i + 0];
    int s1 = srcs_sorted[i + 1];
    int s2 = srcs_sorted[i + 2];
    int s3 = srcs_sorted[i + 3];
    float4 v0 = *(const float4*)(x + (size_t)s0 * D + f);
    float4 v1 = *(const float4*)(x + (size_t)s1 * D + f);
    float4 v2 = *(const float4*)(x + (size_t)s2 * D + f);
    float4 v3 = *(const float4*)(x + (size_t)s3 * D + f);
    a0.x += v0.x; a0.y += v0.y; a0.z += v0.z; a0.w += v0.w;
    a1.x += v1.x; a1.y += v1.y; a1.z += v1.z; a1.w += v1.w;
    a2.x += v2.x; a2.y += v2.y; a2.z += v2.z; a2.w += v2.w;
    a3.x += v3.x; a3.y += v3.y; a3.z += v3.z; a3.w += v3.w;
  }
  for (; i < i1; ++i) {
    float4 v = *(const float4*)(x + (size_t)srcs_sorted[i] * D + f);
    a0.x += v.x; a0.y += v.y; a0.z += v.z; a0.w += v.w;
  }
  float4 r;
  r.x = (a0.x + a1.x) + (a2.x + a3.x);
  r.y = (a0.y + a1.y) + (a2.y + a3.y);
  r.z = (a0.z + a1.z) + (a2.z + a3.z);
  r.w = (a0.w + a1.w) + (a2.w + a3.w);
  *(float4*)(h + (size_t)node * D + f) = r;
}

// ---- Pass 5: out = relu(h @ W + b) ----
// 32 rows x 128 cols per block; 256 threads; 4x4 register tile per thread.
__global__ __launch_bounds__(256) void gcn_gemm_kernel(
    const float* __restrict__ h, const float* __restrict__ W,
    const float* __restrict__ b, float* __restrict__ out) {
  __shared__ float Wl[D * D];   // 64 KB
  for (int i = threadIdx.x; i < D * D; i += 256) Wl[i] = W[i];
  __syncthreads();

  const int c0 = (threadIdx.x & 31) * 4;                    // 4 cols
  const int r0 = blockIdx.x * 32 + (threadIdx.x >> 5) * 4;  // 4 rows
  if (r0 >= N_NODES) return;  // N_NODES % 4 == 0: rowgroups all-or-nothing

  float4 bias = *(const float4*)(b + c0);
  float4 acc0 = bias, acc1 = bias, acc2 = bias, acc3 = bias;
  const float* h0 = h + (size_t)r0 * D;

#define GEMM_STEP(J, HC)                                              \
  {                                                                   \
    float4 wv = *(const float4*)&Wl[(k4 + J) * D + c0];               \
    acc0.x = fmaf(hv0.HC, wv.x, acc0.x);                              \
    acc0.y = fmaf(hv0.HC, wv.y, acc0.y);                              \
    acc0.z = fmaf(hv0.HC, wv.z, acc0.z);                              \
    acc0.w = fmaf(hv0.HC, wv.w, acc0.w);                              \
    acc1.x = fmaf(hv1.HC, wv.x, acc1.x);                              \
    acc1.y = fmaf(hv1.HC, wv.y, acc1.y);                              \
    acc1.z = fmaf(hv1.HC, wv.z, acc1.z);                              \
    acc1.w = fmaf(hv1.HC, wv.w, acc1.w);                              \
    acc2.x = fmaf(hv2.HC, wv.x, acc2.x);                              \
    acc2.y = fmaf(hv2.HC, wv.y, acc2.y);                              \
    acc2.z = fmaf(hv2.HC, wv.z, acc2.z);                              \
    acc2.w = fmaf(hv2.HC, wv.w, acc2.w);                              \
    acc3.x = fmaf(hv3.HC, wv.x, acc3.x);                              \
    acc3.y = fmaf(hv3.HC, wv.y, acc3.y);                              \
    acc3.z = fmaf(hv3.HC, wv.z, acc3.z);                              \
    acc3.w = fmaf(hv3.HC, wv.w, acc3.w);                              \
  }

  for (int k4 = 0; k4 < D; k4 += 4) {
    float4 hv0 = *(const float4*)(h0 + 0 * D + k4);
    float4 hv1 = *(const float4*)(h0 + 1 * D + k4);
    float4 hv2 = *(const float4*)(h0 + 2 * D + k4);
    float4 hv3 = *(const float4*)(h0 + 3 * D + k4);
    GEMM_STEP(0, x)
    GEMM_STEP(1, y)
    GEMM_STEP(2, z)
    GEMM_STEP(3, w)
  }
#undef GEMM_STEP

  float4* o0 = (float4*)(out + (size_t)(r0 + 0) * D + c0);
  float4* o1 = (float4*)(out + (size_t)(r0 + 1) * D + c0);
  float4* o2 = (float4*)(out + (size_t)(r0 + 2) * D + c0);
  float4* o3 = (float4*)(out + (size_t)(r0 + 3) * D + c0);
  float4 z = {0.f, 0.f, 0.f, 0.f};
  float4 t;
  t.x = fmaxf(acc0.x, z.x); t.y = fmaxf(acc0.y, z.y); t.z = fmaxf(acc0.z, z.z); t.w = fmaxf(acc0.w, z.w); *o0 = t;
  t.x = fmaxf(acc1.x, z.x); t.y = fmaxf(acc1.y, z.y); t.z = fmaxf(acc1.z, z.z); t.w = fmaxf(acc1.w, z.w); *o1 = t;
  t.x = fmaxf(acc2.x, z.x); t.y = fmaxf(acc2.y, z.y); t.z = fmaxf(acc2.z, z.z); t.w = fmaxf(acc2.w, z.w); *o2 = t;
  t.x = fmaxf(acc3.x, z.x); t.y = fmaxf(acc3.y, z.y); t.z = fmaxf(acc3.z, z.z); t.w = fmaxf(acc3.w, z.w); *o3 = t;
}

extern "C" void kernel_launch(void* const* d_in, const int* in_sizes, int n_in,
                              void* d_out, int out_size, void* d_ws, size_t ws_size,
                              hipStream_t stream) {
  const float* x   = (const float*)d_in[0];
  const int*   src = (const int*)d_in[1];
  const int*   dst = (const int*)d_in[2];
  const float* W   = (const float*)d_in[3];
  const float* b   = (const float*)d_in[4];
  float* out = (float*)d_out;

  // Workspace layout
  float* h      = (float*)d_ws;                       // 1,280,000 floats
  int*   off    = (int*)(h + (size_t)N_NODES * D);    // 10016 ints (counts -> offsets)
  int*   cursor = off + 10016;                        // 10016 ints
  int*   srcs   = cursor + 10016;                     // 640,000 ints

  // h: no memset needed — gather writes every element.
  hipMemsetAsync(off, 0, 10016 * sizeof(int), stream);

  const int eblocks = (N_EDGES + 255) / 256;  // 2500
  gcn_hist_kernel<<<eblocks, 256, 0, stream>>>(dst, off);
  gcn_scan_kernel<<<1, SCAN_THREADS, 0, stream>>>(off, cursor);
  gcn_fill_kernel<<<eblocks, 256, 0, stream>>>(src, dst, cursor, srcs);
  gcn_gather_kernel<<<(N_NODES + 7) / 8, 256, 0, stream>>>(x, off, srcs, h);
  gcn_gemm_kernel<<<(N_NODES + 31) / 32, 256, 0, stream>>>(h, W, b, out);
}

// Round 4
// 155.938 us; speedup vs baseline: 7.5989x; 1.2403x over previous
//
#include <hip/hip_runtime.h>

#define N_NODES 10000
#define D 128
#define N_EDGES 640000
#define SCAN_THREADS 1024
#define SCAN_CHUNK 10   // 1024*10 = 10240 >= 10000

// ---- Pass 1: histogram of dst -> counts, and per-edge rank (old count) ----
__global__ __launch_bounds__(256) void gcn_hist_kernel(
    const int* __restrict__ dst, int* __restrict__ counts,
    int* __restrict__ rank) {
  int e = blockIdx.x * blockDim.x + threadIdx.x;
  if (e < N_EDGES) rank[e] = atomicAdd(&counts[dst[e]], 1);
}

// ---- Pass 2: single-block exclusive scan of counts -> off (shfl-based) ----
__global__ __launch_bounds__(SCAN_THREADS) void gcn_scan_kernel(
    const int* __restrict__ counts, int* __restrict__ off) {
  __shared__ int wsum[16];
  const int t = threadIdx.x;
  const int lane = t & 63, wv = t >> 6;
  int local[SCAN_CHUNK];
  int sum = 0;
  const int base = t * SCAN_CHUNK;
#pragma unroll
  for (int j = 0; j < SCAN_CHUNK; ++j) {
    int idx = base + j;
    int c = (idx < N_NODES) ? counts[idx] : 0;
    local[j] = c;
    sum += c;
  }
  // inclusive scan of per-thread sums within each wave
  int incl = sum;
  for (int o = 1; o < 64; o <<= 1) {
    int v = __shfl_up(incl, o, 64);
    if (lane >= o) incl += v;
  }
  if (lane == 63) wsum[wv] = incl;
  __syncthreads();
  if (t < 16) {  // exclusive scan of the 16 wave totals (all in wave 0)
    int v = wsum[t];
    int inc2 = v;
    for (int o = 1; o < 16; o <<= 1) {
      int u = __shfl_up(inc2, o, 64);
      if (t >= o) inc2 += u;
    }
    wsum[t] = inc2 - v;
  }
  __syncthreads();
  int run = wsum[wv] + (incl - sum);  // exclusive prefix for this thread
#pragma unroll
  for (int j = 0; j < SCAN_CHUNK; ++j) {
    int idx = base + j;
    if (idx <= N_NODES) off[idx] = run;
    run += local[j];
  }
}

// ---- Pass 3: scatter src ids into dst-sorted order (no atomics) ----
__global__ __launch_bounds__(256) void gcn_fill_kernel(
    const int* __restrict__ src, const int* __restrict__ dst,
    const int* __restrict__ off, const int* __restrict__ rank,
    unsigned short* __restrict__ srcs_sorted) {
  int e = blockIdx.x * blockDim.x + threadIdx.x;
  if (e < N_EDGES) {
    int slot = off[dst[e]] + rank[e];
    srcs_sorted[slot] = (unsigned short)src[e];
  }
}

// ---- Pass 4: per-node gather-sum, no atomics ----
// 32 threads per node (one float4 per thread), 8 nodes per 256-block.
__global__ __launch_bounds__(256) void gcn_gather_kernel(
    const float* __restrict__ x, const int* __restrict__ off,
    const unsigned short* __restrict__ srcs_sorted, float* __restrict__ h) {
  const int node = blockIdx.x * 8 + (threadIdx.x >> 5);
  const int f   = (threadIdx.x & 31) * 4;
  if (node >= N_NODES) return;
  const int i0 = off[node];
  const int i1 = off[node + 1];
  float4 a0 = {0.f, 0.f, 0.f, 0.f}, a1 = a0, a2 = a0, a3 = a0;
  int i = i0;
  for (; i + 4 <= i1; i += 4) {
    int s0 = srcs_sorted[i + 0];
    int s1 = srcs_sorted[i + 1];
    int s2 = srcs_sorted[i + 2];
    int s3 = srcs_sorted[i + 3];
    float4 v0 = *(const float4*)(x + (size_t)s0 * D + f);
    float4 v1 = *(const float4*)(x + (size_t)s1 * D + f);
    float4 v2 = *(const float4*)(x + (size_t)s2 * D + f);
    float4 v3 = *(const float4*)(x + (size_t)s3 * D + f);
    a0.x += v0.x; a0.y += v0.y; a0.z += v0.z; a0.w += v0.w;
    a1.x += v1.x; a1.y += v1.y; a1.z += v1.z; a1.w += v1.w;
    a2.x += v2.x; a2.y += v2.y; a2.z += v2.z; a2.w += v2.w;
    a3.x += v3.x; a3.y += v3.y; a3.z += v3.z; a3.w += v3.w;
  }
  for (; i < i1; ++i) {
    float4 v = *(const float4*)(x + (size_t)srcs_sorted[i] * D + f);
    a0.x += v.x; a0.y += v.y; a0.z += v.z; a0.w += v.w;
  }
  float4 r;
  r.x = (a0.x + a1.x) + (a2.x + a3.x);
  r.y = (a0.y + a1.y) + (a2.y + a3.y);
  r.z = (a0.z + a1.z) + (a2.z + a3.z);
  r.w = (a0.w + a1.w) + (a2.w + a3.w);
  *(float4*)(h + (size_t)node * D + f) = r;
}

// ---- Pass 5: out = relu(h @ W + b) ----
// 32 rows x 128 cols per block; 256 threads; 4x4 register tile per thread.
__global__ __launch_bounds__(256) void gcn_gemm_kernel(
    const float* __restrict__ h, const float* __restrict__ W,
    const float* __restrict__ b, float* __restrict__ out) {
  __shared__ float Wl[D * D];   // 64 KB
  for (int i = threadIdx.x; i < D * D; i += 256) Wl[i] = W[i];
  __syncthreads();

  const int c0 = (threadIdx.x & 31) * 4;                    // 4 cols
  const int r0 = blockIdx.x * 32 + (threadIdx.x >> 5) * 4;  // 4 rows
  if (r0 >= N_NODES) return;  // N_NODES % 4 == 0: rowgroups all-or-nothing

  float4 bias = *(const float4*)(b + c0);
  float4 acc0 = bias, acc1 = bias, acc2 = bias, acc3 = bias;
  const float* h0 = h + (size_t)r0 * D;

#define GEMM_STEP(J, HC)                                              \
  {                                                                   \
    float4 wv = *(const float4*)&Wl[(k4 + J) * D + c0];               \
    acc0.x = fmaf(hv0.HC, wv.x, acc0.x);                              \
    acc0.y = fmaf(hv0.HC, wv.y, acc0.y);                              \
    acc0.z = fmaf(hv0.HC, wv.z, acc0.z);                              \
    acc0.w = fmaf(hv0.HC, wv.w, acc0.w);                              \
    acc1.x = fmaf(hv1.HC, wv.x, acc1.x);                              \
    acc1.y = fmaf(hv1.HC, wv.y, acc1.y);                              \
    acc1.z = fmaf(hv1.HC, wv.z, acc1.z);                              \
    acc1.w = fmaf(hv1.HC, wv.w, acc1.w);                              \
    acc2.x = fmaf(hv2.HC, wv.x, acc2.x);                              \
    acc2.y = fmaf(hv2.HC, wv.y, acc2.y);                              \
    acc2.z = fmaf(hv2.HC, wv.z, acc2.z);                              \
    acc2.w = fmaf(hv2.HC, wv.w, acc2.w);                              \
    acc3.x = fmaf(hv3.HC, wv.x, acc3.x);                              \
    acc3.y = fmaf(hv3.HC, wv.y, acc3.y);                              \
    acc3.z = fmaf(hv3.HC, wv.z, acc3.z);                              \
    acc3.w = fmaf(hv3.HC, wv.w, acc3.w);                              \
  }

  for (int k4 = 0; k4 < D; k4 += 4) {
    float4 hv0 = *(const float4*)(h0 + 0 * D + k4);
    float4 hv1 = *(const float4*)(h0 + 1 * D + k4);
    float4 hv2 = *(const float4*)(h0 + 2 * D + k4);
    float4 hv3 = *(const float4*)(h0 + 3 * D + k4);
    GEMM_STEP(0, x)
    GEMM_STEP(1, y)
    GEMM_STEP(2, z)
    GEMM_STEP(3, w)
  }
#undef GEMM_STEP

  float4* o0 = (float4*)(out + (size_t)(r0 + 0) * D + c0);
  float4* o1 = (float4*)(out + (size_t)(r0 + 1) * D + c0);
  float4* o2 = (float4*)(out + (size_t)(r0 + 2) * D + c0);
  float4* o3 = (float4*)(out + (size_t)(r0 + 3) * D + c0);
  float4 t;
  t.x = fmaxf(acc0.x, 0.f); t.y = fmaxf(acc0.y, 0.f); t.z = fmaxf(acc0.z, 0.f); t.w = fmaxf(acc0.w, 0.f); *o0 = t;
  t.x = fmaxf(acc1.x, 0.f); t.y = fmaxf(acc1.y, 0.f); t.z = fmaxf(acc1.z, 0.f); t.w = fmaxf(acc1.w, 0.f); *o1 = t;
  t.x = fmaxf(acc2.x, 0.f); t.y = fmaxf(acc2.y, 0.f); t.z = fmaxf(acc2.z, 0.f); t.w = fmaxf(acc2.w, 0.f); *o2 = t;
  t.x = fmaxf(acc3.x, 0.f); t.y = fmaxf(acc3.y, 0.f); t.z = fmaxf(acc3.z, 0.f); t.w = fmaxf(acc3.w, 0.f); *o3 = t;
}

extern "C" void kernel_launch(void* const* d_in, const int* in_sizes, int n_in,
                              void* d_out, int out_size, void* d_ws, size_t ws_size,
                              hipStream_t stream) {
  const float* x   = (const float*)d_in[0];
  const int*   src = (const int*)d_in[1];
  const int*   dst = (const int*)d_in[2];
  const float* W   = (const float*)d_in[3];
  const float* b   = (const float*)d_in[4];
  float* out = (float*)d_out;

  // Workspace layout. rank aliases the h region: rank is produced by hist and
  // consumed by fill, both of which complete before gather writes h.
  float*          h      = (float*)d_ws;                    // 1,280,000 floats (5.12 MB)
  int*            rank   = (int*)d_ws;                      // 640,000 ints (alias, pre-gather only)
  int*            counts = (int*)(h + (size_t)N_NODES * D); // 10016 ints
  int*            off    = counts + 10016;                  // 10016 ints
  unsigned short* srcs   = (unsigned short*)(off + 10016);  // 640,000 u16 (1.28 MB)

  hipMemsetAsync(counts, 0, 10016 * sizeof(int), stream);

  const int eblocks = (N_EDGES + 255) / 256;  // 2500
  gcn_hist_kernel<<<eblocks, 256, 0, stream>>>(dst, counts, rank);
  gcn_scan_kernel<<<1, SCAN_THREADS, 0, stream>>>(counts, off);
  gcn_fill_kernel<<<eblocks, 256, 0, stream>>>(src, dst, off, rank, srcs);
  gcn_gather_kernel<<<(N_NODES + 7) / 8, 256, 0, stream>>>(x, off, srcs, h);
  gcn_gemm_kernel<<<(N_NODES + 31) / 32, 256, 0, stream>>>(h, W, b, out);
}